// Round 10
// baseline (78.128 us; speedup 1.0000x reference)
//
#include <hip/hip_runtime.h>
#include <math.h>
#include <stdint.h>

#define B 4
#define T 4096
#define H 2048
#define TT 128            // timesteps per LDS tile
#define NT (T / TT)       // 32 tiles
#define NBAND (H / 32)    // 64 bands of 32 channels
#define THREADS 1024      // 16 waves
#define NSUB 32           // subchunks per tile (THREADS / 32 channels)
#define SUBL (TT / NSUB)  // 4 steps per subchunk

typedef const __attribute__((address_space(1))) uint32_t* gas_ptr;
typedef __attribute__((address_space(3))) uint32_t* las_ptr;

// Stage 8 timesteps x 32 channels (8 rows x 128B = 1KB) global -> LDS.
// Each 128B row = exactly one cache line; bands disjoint -> each HBM line
// fetched exactly once chip-wide.
__device__ __forceinline__ void stage8(const float* gbase, float* lbase, int lane) {
    __builtin_amdgcn_global_load_lds(
        (gas_ptr)(const void*)(gbase + (lane >> 3) * H + (lane & 7) * 4),
        (las_ptr)(void*)lbase, 16, 0, 0);
}

// ---------------------------------------------------------------------------
// Fused WKV, depth-2 prefetch: block = (batch b, band of 32 channels), owns
// all T steps. k,v read ONCE. Tiles of TT=128 rows, TRIPLE-buffered LDS so
// loads are issued two tile-bodies before their deadline (vmcnt wait ~0).
// Wave wv stages rows 8wv..8wv+7 = exactly the rows its subs (2wv,2wv+1)
// consume -> buffer rotation needs no cross-wave reasoning. Two barriers per
// tile keep waves lockstep (round-9 lesson). Counted vmcnt never drains
// stores: steady-state queue [L_j(2)|S_{j-2}(4)|L_{j+1}(2)|S_{j-1}(4)|L_{j+2}(2)].
// ---------------------------------------------------------------------------
__global__ __launch_bounds__(THREADS)
void wkv_fused_kernel(const float* __restrict__ kg,
                      const float* __restrict__ vg,
                      const float* __restrict__ td,
                      const float* __restrict__ tf,
                      float* __restrict__ out) {
    __shared__ float  lk[3][TT][32];    // 3 x 16KB
    __shared__ float  lv[3][TT][32];    // 3 x 16KB
    __shared__ float2 sab[NSUB][32];    // packed (la, lb) partials, 8KB

    int band = blockIdx.x & (NBAND - 1);
    int b    = blockIdx.x >> 6;          // / NBAND
    int tid  = threadIdx.x;
    int lane = tid & 63;
    int wv   = tid >> 6;                 // wave 0..15
    int ch   = tid & 31;
    int sub  = tid >> 5;                 // 0..31

    const float* kbase = kg + (size_t)b * T * H + band * 32;
    const float* vbase = vg + (size_t)b * T * H + band * 32;
    float* obase       = out + (size_t)b * T * H + band * 32;

    int h = band * 32 + ch;
    float ew = expf(-expf(td[h]));
    float eu = expf(tf[h]);

    // powers of ew: ewL = ew^SUBL (=ew^4); ladder up to ew^128 = ew^TT
    float e2 = ew * ew;
    float ewL  = e2 * e2;                // ew^4
    float l2   = ewL * ewL;              // ew^8
    float l4   = l2 * l2;                // ew^16
    float l8   = l4 * l4;                // ew^32
    float l16  = l8 * l8;                // ew^64
    float ewT  = l16 * l16;              // ew^128 = ew^TT
    float ewpow = 1.0f;                  // ewL^sub
    if (sub & 1)  ewpow *= ewL;
    if (sub & 2)  ewpow *= l2;
    if (sub & 4)  ewpow *= l4;
    if (sub & 8)  ewpow *= l8;
    if (sub & 16) ewpow *= l16;

    float Ra = 0.f, Rb = 0.f;            // running state (redundant per thread)

    // wave wv stages rows 8wv..8wv+7 (1 k-group + 1 v-group) = 2 loads/tile
#define ISSUE(tile, bufi)                                                   \
    {                                                                       \
        stage8(kbase + ((size_t)(tile) * TT + 8 * wv) * H,                  \
               &lk[bufi][8 * wv][0], lane);                                 \
        stage8(vbase + ((size_t)(tile) * TT + 8 * wv) * H,                  \
               &lv[bufi][8 * wv][0], lane);                                 \
    }

    ISSUE(0, 0);
    ISSUE(1, 1);
    for (int j = 0; j < NT; ++j) {
        const int cur = j % 3;
        if (j + 2 < NT) ISSUE(j + 2, (j + 2) % 3);
        // wait for tile j's 2 loads (oldest) without draining younger stores
        if (j == 0) {
            asm volatile("s_waitcnt vmcnt(4)" ::: "memory");   // [L1|L2]
        } else if (j == 1) {
            asm volatile("s_waitcnt vmcnt(8)" ::: "memory");   // [L2|S0|L3]
        } else if (j + 2 < NT) {
            asm volatile("s_waitcnt vmcnt(12)" ::: "memory");  // steady
        } else if (j + 1 < NT) {
            asm volatile("s_waitcnt vmcnt(10)" ::: "memory");  // no L(j+2)
        } else {
            asm volatile("s_waitcnt vmcnt(8)" ::: "memory");   // last tile
        }
        __builtin_amdgcn_s_barrier();

        // Phase A: local scan of own 4-step subchunk; ek/ekv stay in registers
        float ek[SUBL], ekv[SUBL];
        float la = 0.f, lb = 0.f;
#pragma unroll
        for (int i = 0; i < SUBL; ++i) {
            int t = sub * SUBL + i;
            float kk = lk[cur][t][ch];
            float vv = lv[cur][t][ch];
            float e  = __expf(kk);
            float ev = e * vv;
            ek[i]  = e;
            ekv[i] = ev;
            la = ew * la + ev;
            lb = ew * lb + e;
        }
        sab[sub][ch] = make_float2(la, lb);
        asm volatile("s_waitcnt lgkmcnt(0)" ::: "memory");
        __builtin_amdgcn_s_barrier();    // sab ready

        // Phase B: single scan chain over 32 partials; capture exclusive
        // prefix when s == sub (before that step's accumulate).
        float ta = 0.f, tb = 0.f, pa = 0.f, pb = 0.f;
#pragma unroll
        for (int s = 0; s < NSUB; ++s) {
            float2 x = sab[s][ch];
            bool cap = (s == sub);
            pa = cap ? ta : pa;
            pb = cap ? tb : pb;
            ta = ewL * ta + x.x;
            tb = ewL * tb + x.y;
        }
        float a2 = ewpow * Ra + pa;      // exclusive carry into this subchunk
        float b2 = ewpow * Rb + pb;
        Ra = ewT * Ra + ta;              // advance running state one tile
        Rb = ewT * Rb + tb;

        // Phase C: emit straight from registers (no LDS, no expf)
#pragma unroll
        for (int i = 0; i < SUBL; ++i) {
            int t = sub * SUBL + i;
            float num = a2 + eu * ekv[i];
            float den = b2 + eu * ek[i] + 1e-8f;
            float inv;
            asm("v_rcp_f32 %0, %1" : "=v"(inv) : "v"(den));
            float r = num * inv;
            __builtin_nontemporal_store(r, obase + ((size_t)j * TT + t) * H + ch);
            a2 = ew * a2 + ekv[i];
            b2 = ew * b2 + ek[i];
        }
    }

    // final states: outputs 1 (a) and 2 (b), each (B, H)
    if (tid < 32) {
        size_t so = (size_t)B * T * H;
        out[so + (size_t)b * H + h] = Ra;
        out[so + (size_t)B * H + (size_t)b * H + h] = Rb;
    }
}

extern "C" void kernel_launch(void* const* d_in, const int* in_sizes, int n_in,
                              void* d_out, int out_size, void* d_ws, size_t ws_size,
                              hipStream_t stream) {
    const float* k  = (const float*)d_in[0];
    const float* v  = (const float*)d_in[1];
    const float* td = (const float*)d_in[2];
    const float* tf = (const float*)d_in[3];
    float* out      = (float*)d_out;

    dim3 grid(B * NBAND);                // 256 blocks = 1 per CU
    wkv_fused_kernel<<<grid, dim3(THREADS), 0, stream>>>(k, v, td, tf, out);
}

// Round 11
// 69.936 us; speedup vs baseline: 1.1171x; 1.1171x over previous
//
#include <hip/hip_runtime.h>
#include <math.h>
#include <stdint.h>

#define B 4
#define T 4096
#define H 2048
#define TT 256            // timesteps per LDS tile
#define NT (T / TT)       // 16 tiles
#define NBAND (H / 32)    // 64 bands of 32 channels
#define THREADS 1024      // 16 waves/CU
#define NSUB 32           // subchunks per tile (THREADS / 32 channels)
#define SUBL (TT / NSUB)  // 8 steps per subchunk

typedef const __attribute__((address_space(1))) uint32_t* gas_ptr;
typedef __attribute__((address_space(3))) uint32_t* las_ptr;

// Stage 8 timesteps x 32 channels (8 rows x 128B = 1KB) global -> LDS.
// Each 128B row = exactly one cache line; bands disjoint -> each HBM line
// fetched exactly once chip-wide.
__device__ __forceinline__ void stage8(const float* gbase, float* lbase, int lane) {
    __builtin_amdgcn_global_load_lds(
        (gas_ptr)(const void*)(gbase + (lane >> 3) * H + (lane & 7) * 4),
        (las_ptr)(void*)lbase, 16, 0, 0);
}

// ---------------------------------------------------------------------------
// Fused WKV: block = (batch b, band of 32 channels), owns all T=4096 steps.
// k,v read ONCE. Per tile: A) per-thread 8-step local scan (__expf), keeping
// ek / ek*v in REGISTERS (no LDS write-back); B) all-thread redundant scan
// over the 32 packed float2 partials (cndmask capture at s==sub); C) emit
// from the exclusive carry using the register-resident ek/ekv, v_rcp divide.
// 2 barriers/tile: post-A (sab ready; lk/lv reads done -> buffer reusable)
// and the top-of-loop staging barrier. Counted vmcnt never drains stores:
// per wave per tile the queue is [L_j(4) | S_{j-1}(8) | L_{j+1}(4)].
// NOTE (rounds 9/10): removing the top barrier OR going depth-2 with smaller
// tiles both REGRESS — this 2-barrier depth-1 TT=256 point is the measured
// optimum (70.1 us = 91% of the 402MB/6.3TB/s copy roofline).
// ---------------------------------------------------------------------------
__global__ __launch_bounds__(THREADS)
void wkv_fused_kernel(const float* __restrict__ kg,
                      const float* __restrict__ vg,
                      const float* __restrict__ td,
                      const float* __restrict__ tf,
                      float* __restrict__ out) {
    __shared__ float  lk[2][TT][32];    // 2 x 32KB
    __shared__ float  lv[2][TT][32];    // 2 x 32KB
    __shared__ float2 sab[NSUB][32];    // packed (la, lb) partials, 8KB

    int band = blockIdx.x & (NBAND - 1);
    int b    = blockIdx.x >> 6;          // / NBAND
    int tid  = threadIdx.x;
    int lane = tid & 63;
    int wv   = tid >> 6;                 // wave 0..15
    int ch   = tid & 31;
    int sub  = tid >> 5;                 // 0..31

    const float* kbase = kg + (size_t)b * T * H + band * 32;
    const float* vbase = vg + (size_t)b * T * H + band * 32;
    float* obase       = out + (size_t)b * T * H + band * 32;

    int h = band * 32 + ch;
    float ew = expf(-expf(td[h]));
    float eu = expf(tf[h]);

    // powers of ew: ewL = ew^SUBL (=ew^8); ladder up to ew^256
    float e2 = ew * ew, e4 = e2 * e2;
    float ewL  = e4 * e4;                // ew^8
    float l2   = ewL * ewL;              // ew^16
    float l4   = l2 * l2;                // ew^32
    float l8   = l4 * l4;                // ew^64
    float l16  = l8 * l8;                // ew^128
    float ewT  = l16 * l16;              // ew^256 = ew^TT
    float ewpow = 1.0f;                  // ewL^sub
    if (sub & 1)  ewpow *= ewL;
    if (sub & 2)  ewpow *= l2;
    if (sub & 4)  ewpow *= l4;
    if (sub & 8)  ewpow *= l8;
    if (sub & 16) ewpow *= l16;

    float Ra = 0.f, Rb = 0.f;            // running state (redundant per thread)

    // 16 waves x (2 k-groups + 2 v-groups) of 8 rows each = whole 256-row tile
#define ISSUE(tile, bufi)                                                   \
    {                                                                       \
        _Pragma("unroll")                                                   \
        for (int ii = 0; ii < 2; ++ii) {                                    \
            int g = wv * 2 + ii;                                            \
            stage8(kbase + ((size_t)(tile) * TT + 8 * g) * H,               \
                   &lk[bufi][8 * g][0], lane);                              \
            stage8(vbase + ((size_t)(tile) * TT + 8 * g) * H,               \
                   &lv[bufi][8 * g][0], lane);                              \
        }                                                                   \
    }

    ISSUE(0, 0);
    for (int j = 0; j < NT; ++j) {
        const int cur = j & 1;
        if (j + 1 < NT) ISSUE(j + 1, cur ^ 1);
        // wait for tile j's 4 loads (oldest) without draining younger stores
        if (j == 0) {
            asm volatile("s_waitcnt vmcnt(4)" ::: "memory");   // [L0|L1]
        } else if (j + 1 < NT) {
            asm volatile("s_waitcnt vmcnt(12)" ::: "memory");  // [Lj|S(8)|Lj+1]
        } else {
            asm volatile("s_waitcnt vmcnt(8)" ::: "memory");   // [Llast|S(8)]
        }
        __builtin_amdgcn_s_barrier();

        // Phase A: local scan of own 8-step subchunk; ek/ekv stay in registers
        float ek[SUBL], ekv[SUBL];
        float la = 0.f, lb = 0.f;
#pragma unroll
        for (int i = 0; i < SUBL; ++i) {
            int t = sub * SUBL + i;
            float kk = lk[cur][t][ch];
            float vv = lv[cur][t][ch];
            float e  = __expf(kk);
            float ev = e * vv;
            ek[i]  = e;
            ekv[i] = ev;
            la = ew * la + ev;
            lb = ew * lb + e;
        }
        sab[sub][ch] = make_float2(la, lb);
        asm volatile("s_waitcnt lgkmcnt(0)" ::: "memory");
        __builtin_amdgcn_s_barrier();    // sab ready; lk/lv[cur] reads done

        // Phase B: single scan chain over 32 partials; capture exclusive
        // prefix when s == sub (before that step's accumulate).
        float ta = 0.f, tb = 0.f, pa = 0.f, pb = 0.f;
#pragma unroll
        for (int s = 0; s < NSUB; ++s) {
            float2 x = sab[s][ch];
            bool cap = (s == sub);
            pa = cap ? ta : pa;
            pb = cap ? tb : pb;
            ta = ewL * ta + x.x;
            tb = ewL * tb + x.y;
        }
        float a2 = ewpow * Ra + pa;      // exclusive carry into this subchunk
        float b2 = ewpow * Rb + pb;
        Ra = ewT * Ra + ta;              // advance running state one tile
        Rb = ewT * Rb + tb;

        // Phase C: emit straight from registers (no LDS, no expf)
#pragma unroll
        for (int i = 0; i < SUBL; ++i) {
            int t = sub * SUBL + i;
            float num = a2 + eu * ekv[i];
            float den = b2 + eu * ek[i] + 1e-8f;
            float inv;
            asm("v_rcp_f32 %0, %1" : "=v"(inv) : "v"(den));
            float r = num * inv;
            __builtin_nontemporal_store(r, obase + ((size_t)j * TT + t) * H + ch);
            a2 = ew * a2 + ekv[i];
            b2 = ew * b2 + ek[i];
        }
        // no barrier needed: buffer `cur` reads finished before post-A barrier
    }

    // final states: outputs 1 (a) and 2 (b), each (B, H)
    if (tid < 32) {
        size_t so = (size_t)B * T * H;
        out[so + (size_t)b * H + h] = Ra;
        out[so + (size_t)B * H + (size_t)b * H + h] = Rb;
    }
}

extern "C" void kernel_launch(void* const* d_in, const int* in_sizes, int n_in,
                              void* d_out, int out_size, void* d_ws, size_t ws_size,
                              hipStream_t stream) {
    const float* k  = (const float*)d_in[0];
    const float* v  = (const float*)d_in[1];
    const float* td = (const float*)d_in[2];
    const float* tf = (const float*)d_in[3];
    float* out      = (float*)d_out;

    dim3 grid(B * NBAND);                // 256 blocks = 1 per CU
    wkv_fused_kernel<<<grid, dim3(THREADS), 0, stream>>>(k, v, td, tf, out);
}